// Round 25
// baseline (158.123 us; speedup 1.0000x reference)
//
#include <hip/hip_runtime.h>
#include <hip/hip_bf16.h>
#include <cstdint>

#define DM   1024
#define NH   16
#define DKK  64
#define BB   4
#define SS   2048

typedef __attribute__((ext_vector_type(8)))  short short8;
typedef __attribute__((ext_vector_type(4)))  float f32x4;
typedef __attribute__((ext_vector_type(16))) float f32x16;

__device__ __forceinline__ unsigned short f2bf(float f) {
    union { float f; uint32_t u; } v; v.f = f;
    uint32_t u = v.u;
    uint32_t r = (u + 0x7FFFu + ((u >> 16) & 1u)) >> 16;   // RNE
    return (unsigned short)r;
}

#define GLL(src, dst) __builtin_amdgcn_global_load_lds(                      \
        (__attribute__((address_space(1))) void*)(src),                      \
        (__attribute__((address_space(3))) void*)(dst), 16, 0, 0)

// ---------------- fp32 -> bf16 convert + PRE-SWIZZLE (4 weight matrices) ----------------
// W_sw[j][kb*8..] = W[j][kbs*8..], kbs = (kb&~7)|((kb^j)&7)
__global__ void cvt_w(const float* __restrict__ wq, const float* __restrict__ wk,
                      const float* __restrict__ wv, const float* __restrict__ wo,
                      unsigned short* __restrict__ dst)
{
    int i = blockIdx.x * 256 + threadIdx.x;      // 16B-block id: 4 * 1024 * 128
    int a = i >> 17;
    int r = i & 131071;
    int j = r >> 7, kb = r & 127;
    int kbs = (kb & ~7) | ((kb ^ j) & 7);
    const float* s = (a == 0 ? wq : a == 1 ? wk : a == 2 ? wv : wo) + (size_t)j * 1024 + kbs * 8;
    float4 f0 = *(const float4*)(s);
    float4 f1 = *(const float4*)(s + 4);
    union { uint32_t u[4]; short8 s8; } c;
    asm("v_cvt_pk_bf16_f32 %0, %1, %2" : "=v"(c.u[0]) : "v"(f0.x), "v"(f0.y));
    asm("v_cvt_pk_bf16_f32 %0, %1, %2" : "=v"(c.u[1]) : "v"(f0.z), "v"(f0.w));
    asm("v_cvt_pk_bf16_f32 %0, %1, %2" : "=v"(c.u[2]) : "v"(f1.x), "v"(f1.y));
    asm("v_cvt_pk_bf16_f32 %0, %1, %2" : "=v"(c.u[3]) : "v"(f1.z), "v"(f1.w));
    *(short8*)(dst + ((size_t)a << 20) + (size_t)j * 1024 + kb * 8) = c.s8;
}

// ------ merged QKV GEMM: 512 thr, serial B, depth-2 reg-prefetched fp32 A, fused cvt ------
// r23 base (128x128 tile, 32KB LDS, 4 blocks/CU = 32 waves/CU) + X/Y register prefetch of A.
// ORDER FIX (r24 NaN): a compiler fence after the B GLLs pins issue order B(t) -> A(t+2), so
// the ledger holds: outstanding at drain = olderA(4) + B(t)(2) + newA(4) = 10 -> vmcnt(4)
// retires olderA + B(t). Tail t=14,15: vmcnt(0) (order-insensitive).
__global__ __launch_bounds__(512) void gemm_qkv(
        const float* __restrict__ Aq, const float* __restrict__ Ak, const float* __restrict__ Av,
        const unsigned short* __restrict__ Wq, const unsigned short* __restrict__ Wk,
        const unsigned short* __restrict__ Wv,
        const float* __restrict__ bq, const float* __restrict__ bk, const float* __restrict__ bv,
        unsigned short* __restrict__ Qo, unsigned short* __restrict__ Ko,
        unsigned short* __restrict__ Vo, const float qscale)
{
    const int orig = blockIdx.z * 512 + blockIdx.y * 8 + blockIdx.x;
    const int wid  = (orig & 7) * 192 + (orig >> 3);   // bijective XCD swizzle
    const int z    = wid >> 9;
    const int rem  = wid & 511;
    const int brow = (rem >> 3) * 128;
    const int bcol = (rem & 7) * 128;

    const float* A           = (z == 0) ? Aq : (z == 1) ? Ak : Av;
    const unsigned short* Bw = (z == 0) ? Wq : (z == 1) ? Wk : Wv;
    const float* bias        = (z == 0) ? bq : (z == 1) ? bk : bv;

    __shared__ __align__(16) unsigned short lA[128 * 64];
    __shared__ __align__(16) unsigned short lB[128 * 64];
    const int tid = threadIdx.x;
    const int w = tid >> 6, l = tid & 63;          // 8 waves
    const int wr = (w >> 1) * 32, wc = (w & 1) * 64;   // 4M x 2N, per-wave 32x64
    const int lrow = l & 15;
    const int hi = l >> 4;
    const int sr = l >> 3;
    const int scb = l & 7;
    f32x4 acc[2][4] = {};

    const float* aga[2];
    const unsigned short* bga[2];
    int awb[2], lbo[2];
#pragma unroll
    for (int i = 0; i < 2; ++i) {
        const int chunk = w * 2 + i;
        const int r = chunk * 8 + sr;
        aga[i] = A  + (size_t)(brow + r) * 1024 + scb * 8;
        bga[i] = Bw + (size_t)(bcol + r) * 1024 + scb * 8;
        awb[i] = chunk * 1024 + sr * 128 + ((scb ^ sr) << 4);
        lbo[i] = chunk * 512;
    }

    f32x4 aX[2][2], aY[2][2];   // [chunk][half] fp32 prefetch regs

#define QKV_LD(R, KT)                                                    \
    { _Pragma("unroll") for (int i = 0; i < 2; ++i) {                    \
        R[i][0] = *(const f32x4*)(aga[i] + (KT) * 64);                   \
        R[i][1] = *(const f32x4*)(aga[i] + (KT) * 64 + 4); } }

#define QKV_CVTWR(R)                                                     \
    { _Pragma("unroll") for (int i = 0; i < 2; ++i) {                    \
        union { uint32_t u[4]; short8 s8; } c;                           \
        asm("v_cvt_pk_bf16_f32 %0, %1, %2" : "=v"(c.u[0]) : "v"(R[i][0][0]), "v"(R[i][0][1])); \
        asm("v_cvt_pk_bf16_f32 %0, %1, %2" : "=v"(c.u[1]) : "v"(R[i][0][2]), "v"(R[i][0][3])); \
        asm("v_cvt_pk_bf16_f32 %0, %1, %2" : "=v"(c.u[2]) : "v"(R[i][1][0]), "v"(R[i][1][1])); \
        asm("v_cvt_pk_bf16_f32 %0, %1, %2" : "=v"(c.u[3]) : "v"(R[i][1][2]), "v"(R[i][1][3])); \
        *(short8*)((char*)lA + awb[i]) = c.s8; } }

#define QKV_MFMA                                                                              \
    {                                                                                         \
        __builtin_amdgcn_s_setprio(1);                                                        \
        _Pragma("unroll") for (int kk = 0; kk < 2; ++kk) {                                    \
            short8 af[2], bf[4];                                                              \
            _Pragma("unroll") for (int m = 0; m < 2; ++m) {                                   \
                const int row = wr + m * 16 + lrow;                                           \
                const int pb = (kk * 4 + hi) ^ (row & 7);                                     \
                af[m] = *(const short8*)((const char*)lA + row * 128 + (pb << 4));            \
            }                                                                                 \
            _Pragma("unroll") for (int n = 0; n < 4; ++n) {                                   \
                const int row = wc + n * 16 + lrow;                                           \
                const int pb = (kk * 4 + hi) ^ (row & 7);                                     \
                bf[n] = *(const short8*)((const char*)lB + row * 128 + (pb << 4));            \
            }                                                                                 \
            _Pragma("unroll") for (int m = 0; m < 2; ++m)                                     \
            _Pragma("unroll") for (int n = 0; n < 4; ++n)                                     \
                acc[m][n] = __builtin_amdgcn_mfma_f32_16x16x32_bf16(af[m], bf[n], acc[m][n], 0, 0, 0); \
        }                                                                                     \
        __builtin_amdgcn_s_setprio(0);                                                        \
    }

    // prologue: X <- A(0), Y <- A(1)
    QKV_LD(aX, 0);
    QKV_LD(aY, 1);
    asm volatile("" ::: "memory");      // pin: prologue A loads precede loop-body B GLLs

    for (int t = 0; t < 14; t += 2) {
        // even iter: B(t) GLL; FENCE; cvt X=A(t); reload X <- A(t+2)
#pragma unroll
        for (int i = 0; i < 2; ++i) GLL(bga[i] + t * 64, lB + lbo[i]);
        asm volatile("" ::: "memory");  // pin: B(t) issued before A(t+2) loads
        QKV_CVTWR(aX);
        QKV_LD(aX, t + 2);
        asm volatile("s_waitcnt vmcnt(4) lgkmcnt(0)" ::: "memory");
        __builtin_amdgcn_s_barrier();
        QKV_MFMA;
        asm volatile("" ::: "memory");
        __builtin_amdgcn_s_barrier();
        // odd iter: B(t+1) GLL; FENCE; cvt Y=A(t+1); reload Y <- A(t+3)
#pragma unroll
        for (int i = 0; i < 2; ++i) GLL(bga[i] + (t + 1) * 64, lB + lbo[i]);
        asm volatile("" ::: "memory");
        QKV_CVTWR(aY);
        QKV_LD(aY, t + 3);
        asm volatile("s_waitcnt vmcnt(4) lgkmcnt(0)" ::: "memory");
        __builtin_amdgcn_s_barrier();
        QKV_MFMA;
        asm volatile("" ::: "memory");
        __builtin_amdgcn_s_barrier();
    }
    // t = 14: B(14); cvt X=A(14); full drain
#pragma unroll
    for (int i = 0; i < 2; ++i) GLL(bga[i] + 14 * 64, lB + lbo[i]);
    asm volatile("" ::: "memory");
    QKV_CVTWR(aX);
    asm volatile("s_waitcnt vmcnt(0) lgkmcnt(0)" ::: "memory");
    __builtin_amdgcn_s_barrier();
    QKV_MFMA;
    asm volatile("" ::: "memory");
    __builtin_amdgcn_s_barrier();
    // t = 15: B(15); cvt Y=A(15); full drain
#pragma unroll
    for (int i = 0; i < 2; ++i) GLL(bga[i] + 15 * 64, lB + lbo[i]);
    asm volatile("" ::: "memory");
    QKV_CVTWR(aY);
    asm volatile("s_waitcnt vmcnt(0) lgkmcnt(0)" ::: "memory");
    __builtin_amdgcn_s_barrier();
    QKV_MFMA;

#undef QKV_LD
#undef QKV_CVTWR
#undef QKV_MFMA

    const float ascale = (z == 0) ? qscale : 1.0f;
#pragma unroll
    for (int m = 0; m < 2; ++m) {
#pragma unroll
        for (int n = 0; n < 4; ++n) {
            const int i0 = brow + wr + m * 16 + hi * 4;
            const int j  = bcol + wc + n * 16 + lrow;
            const float bj = bias[j];
            const int hh = j >> 6, d = j & 63;
            if (z < 2) {
                unsigned short* Cb = (z == 0) ? Qo : Ko;
#pragma unroll
                for (int t = 0; t < 4; ++t) {
                    const int i = i0 + t;
                    const int b = i >> 11, s = i & 2047;
                    Cb[(((size_t)(b * NH + hh) * SS) + s) * DKK + d] = f2bf((acc[m][n][t] + bj) * ascale);
                }
            } else {   // V^T
                const int b = i0 >> 11, s0 = i0 & 2047;
                ushort4 pk;
                pk.x = f2bf(acc[m][n][0] + bj);
                pk.y = f2bf(acc[m][n][1] + bj);
                pk.z = f2bf(acc[m][n][2] + bj);
                pk.w = f2bf(acc[m][n][3] + bj);
                *(ushort4*)(Vo + (((size_t)(b * NH + hh) * DKK) + d) * SS + s0) = pk;
            }
        }
    }
}

// ---------------- final projection GEMM: bf16 A reg-staged swizzled, depth-2, fp32 out ------
__global__ __launch_bounds__(256) void gemm_out(
        const unsigned short* __restrict__ A,
        const unsigned short* __restrict__ Bw,
        const float* __restrict__ bias,
        float* __restrict__ Cout)
{
    const int orig = blockIdx.y * 8 + blockIdx.x;
    const int wid  = (orig & 7) * 64 + (orig >> 3);
    const int brow = (wid >> 3) * 128;
    const int bcol = (wid & 7) * 128;

    __shared__ __align__(16) unsigned short lA[128 * 64];
    __shared__ __align__(16) unsigned short lB[2][128 * 64];

    const int tid = threadIdx.x;
    const int w = tid >> 6, l = tid & 63;
    const int wr = (w >> 1) * 64, wc = (w & 1) * 64;
    const int lrow = l & 15;
    const int hi = l >> 4;
    const int sr = l >> 3, scb = l & 7;

    const unsigned short* aga[4];
    const unsigned short* bga[4];
    int awb[4], lbo[4];
#pragma unroll
    for (int i = 0; i < 4; ++i) {
        const int chunk = w * 4 + i;
        const int r = chunk * 8 + sr;
        aga[i] = A  + (size_t)(brow + r) * 1024 + scb * 8;
        bga[i] = Bw + (size_t)(bcol + r) * 1024 + scb * 8;
        awb[i] = chunk * 1024 + sr * 128 + ((scb ^ sr) << 4);
        lbo[i] = chunk * 512;
    }

    short8 aX[4], aY[4];
    f32x4 acc[4][4] = {};

#pragma unroll
    for (int i = 0; i < 4; ++i) GLL(bga[i], lB[0] + lbo[i]);
#pragma unroll
    for (int i = 0; i < 4; ++i) aX[i] = *(const short8*)(aga[i]);
#pragma unroll
    for (int i = 0; i < 4; ++i) aY[i] = *(const short8*)(aga[i] + 64);

#define OUT_WR(CUR)                                                     \
    _Pragma("unroll")                                                   \
    for (int i = 0; i < 4; ++i)                                         \
        *(short8*)((char*)lA + awb[i]) = CUR[i];

#define OUT_MFMA(LB)                                                                              \
    {                                                                                             \
        const unsigned short* lb = (LB);                                                          \
        __builtin_amdgcn_s_setprio(1);                                                            \
        _Pragma("unroll")                                                                         \
        for (int kk = 0; kk < 2; ++kk) {                                                          \
            short8 af[4], bf[4];                                                                  \
            _Pragma("unroll")                                                                     \
            for (int m = 0; m < 4; ++m) {                                                         \
                const int row = wr + m * 16 + lrow;                                               \
                const int pb = (kk * 4 + hi) ^ (row & 7);                                         \
                af[m] = *(const short8*)((const char*)lA + row * 128 + (pb << 4));                \
            }                                                                                     \
            _Pragma("unroll")                                                                     \
            for (int n = 0; n < 4; ++n) {                                                         \
                const int row = wc + n * 16 + lrow;                                               \
                const int pb = (kk * 4 + hi) ^ (row & 7);                                         \
                bf[n] = *(const short8*)((const char*)lb + row * 128 + (pb << 4));                \
            }                                                                                     \
            _Pragma("unroll")                                                                     \
            for (int m = 0; m < 4; ++m)                                                           \
                _Pragma("unroll")                                                                 \
                for (int n = 0; n < 4; ++n)                                                       \
                    acc[m][n] = __builtin_amdgcn_mfma_f32_16x16x32_bf16(af[m], bf[n], acc[m][n], 0, 0, 0); \
        }                                                                                         \
        __builtin_amdgcn_s_setprio(0);                                                            \
    }

    for (int t = 0; t < 14; t += 2) {
        OUT_WR(aX);
        {
            const int ko = (t + 2) * 64;
#pragma unroll
            for (int i = 0; i < 4; ++i) aX[i] = *(const short8*)(aga[i] + ko);
            const int kb = (t + 1) * 64;
#pragma unroll
            for (int i = 0; i < 4; ++i) GLL(bga[i] + kb, lB[1] + lbo[i]);
        }
        asm volatile("s_waitcnt vmcnt(8) lgkmcnt(0)" ::: "memory");
        __builtin_amdgcn_s_barrier();
        OUT_MFMA(lB[0]);
        asm volatile("" ::: "memory");
        __builtin_amdgcn_s_barrier();

        OUT_WR(aY);
        {
            const int ko = (t + 3) * 64;
#pragma unroll
            for (int i = 0; i < 4; ++i) aY[i] = *(const short8*)(aga[i] + ko);
            const int kb = (t + 2) * 64;
#pragma unroll
            for (int i = 0; i < 4; ++i) GLL(bga[i] + kb, lB[0] + lbo[i]);
        }
        asm volatile("s_waitcnt vmcnt(8) lgkmcnt(0)" ::: "memory");
        __builtin_amdgcn_s_barrier();
        OUT_MFMA(lB[1]);
        asm volatile("" ::: "memory");
        __builtin_amdgcn_s_barrier();
    }
    OUT_WR(aX);
#pragma unroll
    for (int i = 0; i < 4; ++i) GLL(bga[i] + 15 * 64, lB[1] + lbo[i]);
    asm volatile("s_waitcnt vmcnt(4) lgkmcnt(0)" ::: "memory");
    __builtin_amdgcn_s_barrier();
    OUT_MFMA(lB[0]);
    asm volatile("" ::: "memory");
    __builtin_amdgcn_s_barrier();
    OUT_WR(aY);
    asm volatile("s_waitcnt vmcnt(0) lgkmcnt(0)" ::: "memory");
    __builtin_amdgcn_s_barrier();
    OUT_MFMA(lB[1]);

#pragma unroll
    for (int m = 0; m < 4; ++m) {
#pragma unroll
        for (int n = 0; n < 4; ++n) {
            const int i0 = brow + wr + m * 16 + (l >> 4) * 4;
            const int j  = bcol + wc + n * 16 + lrow;
            const float bj = bias[j];
#pragma unroll
            for (int t = 0; t < 4; ++t)
                Cout[(size_t)(i0 + t) * DM + j] = acc[m][n][t] + bj;
        }
    }
#undef OUT_WR
#undef OUT_MFMA
}

// ---------------- causal flash attention (round-7, unchanged) ----------------
__global__ __launch_bounds__(256) void attn_kernel(
        const unsigned short* __restrict__ Q,
        const unsigned short* __restrict__ K,
        const unsigned short* __restrict__ Vt,
        unsigned short* __restrict__ AO)
{
    const int flat = blockIdx.y * 16 + blockIdx.x;      // grid (16, 64)
    const int r8 = flat & 7, k8 = flat >> 3;
    const int bh = r8 * 8 + (k8 & 7);                   // 8 heads per XCD-residue (L2 share)
    const int qchunk = 15 - (k8 >> 3);                  // LPT: long blocks first
    const int tid = threadIdx.x;
    const int w = tid >> 6, l = tid & 63;
    const int ln = l & 31, h = l >> 5;
    const int qb = qchunk * 128;
    const int q0w = qb + w * 32;

    __shared__ __align__(16) char lK[2][4096];
    __shared__ __align__(16) char lV[2][4096];

    const unsigned short* Qp = Q  + ((size_t)bh * SS + q0w) * DKK;
    const unsigned short* Kp = K  + (size_t)bh * SS * DKK;
    const unsigned short* Vp = Vt + (size_t)bh * DKK * SS;

    const int srow = tid >> 3, scb = tid & 7;
    const int swb = srow * 128 + ((scb * 16) ^ ((srow & 7) << 4));
    const unsigned short* ksrc = Kp + srow * DKK + scb * 8;            // + t*2048
    const int vd = (scb < 4) ? srow : (srow + 32);
    const unsigned short* vsrc = Vp + (size_t)vd * SS + (scb & 3) * 8; // + t*32

    int ka[4], va[4];
#pragma unroll
    for (int ks = 0; ks < 4; ++ks)
        ka[ks] = ln * 128 + ((ks * 32 + h * 16) ^ ((ln & 7) << 4));
#pragma unroll
    for (int c = 0; c < 4; ++c)
        va[c] = ln * 128 + ((c * 32 + h * 16) ^ ((ln & 7) << 4));

    short8 qf[4];
#pragma unroll
    for (int ks = 0; ks < 4; ++ks)
        qf[ks] = *(const short8*)(Qp + (size_t)ln * DKK + ks * 16 + h * 8);

    f32x16 o0 = {}, o1 = {};
    float lsum = 0.f;

    const int Tc = qb / 32;
    const int NT = Tc + 4;

    auto compute = [&](int t, int buf) {
        const char* kb = lK[buf];
        const char* vb = lV[buf];
        short8 kf[4];
#pragma unroll
        for (int ks = 0; ks < 4; ++ks) kf[ks] = *(const short8*)(kb + ka[ks]);

        f32x16 s = {};
        __builtin_amdgcn_s_setprio(1);
#pragma unroll
        for (int ks = 0; ks < 4; ++ks)
            s = __builtin_amdgcn_mfma_f32_32x32x16_bf16(kf[ks], qf[ks], s, 0, 0, 0);
        __builtin_amdgcn_s_setprio(0);

        const bool diag = (t == Tc + w);
#pragma unroll
        for (int r = 0; r < 16; ++r) {
            float e;
            asm("v_exp_f32 %0, %1" : "=v"(e) : "v"(s[r]));   // 2^s (Q pre-scaled)
            if (diag) {
                const int crow = (r & 3) + 8 * (r >> 2) + 4 * h;
                e = (crow > ln) ? 0.f : e;
            }
            s[r] = e;
            lsum += e;
        }

        uint32_t pk[8];
#pragma unroll
        for (int i = 0; i < 8; ++i) {
            uint32_t d;
            asm("v_cvt_pk_bf16_f32 %0, %1, %2" : "=v"(d) : "v"(s[2 * i]), "v"(s[2 * i + 1]));
            pk[i] = d;
        }
        asm("v_permlane32_swap_b32 %0, %1" : "+v"(pk[0]), "+v"(pk[2]));
        asm("v_permlane32_swap_b32 %0, %1" : "+v"(pk[1]), "+v"(pk[3]));
        asm("v_permlane32_swap_b32 %0, %1" : "+v"(pk[4]), "+v"(pk[6]));
        asm("v_permlane32_swap_b32 %0, %1" : "+v"(pk[5]), "+v"(pk[7]));

        union Ux { uint32_t u[4]; short8 s8; } pa0, pa1;
        pa0.u[0] = pk[0]; pa0.u[1] = pk[1]; pa0.u[2] = pk[2]; pa0.u[3] = pk[3];
        pa1.u[0] = pk[4]; pa1.u[1] = pk[5]; pa1.u[2] = pk[6]; pa1.u[3] = pk[7];

        short8 vf00 = *(const short8*)(vb + va[0]);
        short8 vf10 = *(const short8*)(vb + va[1]);
        short8 vf01 = *(const short8*)(vb + va[2]);
        short8 vf11 = *(const short8*)(vb + va[3]);

        __builtin_amdgcn_s_setprio(1);
        o0 = __builtin_amdgcn_mfma_f32_32x32x16_bf16(pa0.s8, vf00, o0, 0, 0, 0);
        o0 = __builtin_amdgcn_mfma_f32_32x32x16_bf16(pa1.s8, vf10, o0, 0, 0, 0);
        o1 = __builtin_amdgcn_mfma_f32_32x32x16_bf16(pa0.s8, vf01, o1, 0, 0, 0);
        o1 = __builtin_amdgcn_mfma_f32_32x32x16_bf16(pa1.s8, vf11, o1, 0, 0, 0);
        __builtin_amdgcn_s_setprio(0);
    };

    short8 kA = *(const short8*)(ksrc);
    short8 vA = *(const short8*)(vsrc);
    *(short8*)(&lK[0][swb]) = kA;
    *(short8*)(&lV[0][swb]) = vA;
    kA = *(const short8*)(ksrc + 2048);
    vA = *(const short8*)(vsrc + 32);
    short8 kB = {}, vB = {};
    __syncthreads();

    int t = 0, buf = 0;
    for (;;) {
        if (t + 2 < NT) {
            kB = *(const short8*)(ksrc + (size_t)(t + 2) * 2048);
            vB = *(const short8*)(vsrc + (size_t)(t + 2) * 32);
        }
        if (t <= Tc + w) compute(t, buf);
        if (t + 1 < NT) {
            *(short8*)(&lK[buf ^ 1][swb]) = kA;
            *(short8*)(&lV[buf ^ 1][swb]) = vA;
        }
        __syncthreads();
        buf ^= 1;
        if (++t == NT) break;

        if (t + 2 < NT) {
            kA = *(const short8*)(ksrc + (size_t)(t + 2) * 2048);
            vA = *(const short8*)(vsrc + (size_t)(t + 2) * 32);
        }
        if (t <= Tc + w) compute(t, buf);
        if (t + 1 < NT) {
            *(short8*)(&lK[buf ^ 1][swb]) = kB;
            *(short8*)(&lV[buf ^ 1][swb]) = vB;
        }
        __syncthreads();
        buf ^= 1;
        if (++t == NT) break;
    }

    lsum += __shfl_xor(lsum, 32, 64);
    const float rcp = 1.0f / lsum;

    const int bb = bh >> 4, hh = bh & 15;
#pragma unroll
    for (int r = 0; r < 16; ++r) {
        const int crow = (r & 3) + 8 * (r >> 2) + 4 * h;
        const float rl = __shfl(rcp, crow, 64);
        const size_t row = (size_t)(bb * SS + q0w + crow) * DM + hh * DKK;
        AO[row + ln]      = f2bf(o0[r] * rl);
        AO[row + 32 + ln] = f2bf(o1[r] * rl);
    }
}

extern "C" void kernel_launch(void* const* d_in, const int* in_sizes, int n_in,
                              void* d_out, int out_size, void* d_ws, size_t ws_size,
                              hipStream_t stream)
{
    const float* query  = (const float*)d_in[0];
    const float* key_in = (const float*)d_in[1];
    const float* value  = (const float*)d_in[2];
    const float* Wq = (const float*)d_in[3];
    const float* bq = (const float*)d_in[4];
    const float* Wk = (const float*)d_in[5];
    const float* bk = (const float*)d_in[6];
    const float* Wv = (const float*)d_in[7];
    const float* bv = (const float*)d_in[8];
    const float* Wo = (const float*)d_in[9];
    const float* bo = (const float*)d_in[10];

    const size_t NACT = (size_t)BB * SS * DM;   // 8388608
    const size_t NWT  = (size_t)DM * DM;        // 1048576

    unsigned short* ws  = (unsigned short*)d_ws;
    unsigned short* wqb = ws;
    unsigned short* wkb = wqb + NWT;
    unsigned short* wvb = wkb + NWT;
    unsigned short* wob = wvb + NWT;
    unsigned short* Qb  = wob + NWT;
    unsigned short* Kb  = Qb + NACT;
    unsigned short* Vtb = Kb + NACT;
    unsigned short* AOb = Vtb + NACT;

    cvt_w<<<2048, 256, 0, stream>>>(Wq, Wk, Wv, Wo, ws);

    const float QSCALE = 0.125f * 1.44269504088896f;   // 1/sqrt(64) * log2(e)
    dim3 gq(8, 64, 3);   // 1536 blocks
    gemm_qkv<<<gq, 512, 0, stream>>>(query, key_in, value, wqb, wkb, wvb,
                                     bq, bk, bv, Qb, Kb, Vtb, QSCALE);

    attn_kernel<<<dim3(16, 64), 256, 0, stream>>>(Qb, Kb, Vtb, AOb);

    dim3 gg(DM / 128, (BB * SS) / 128);   // (8, 64)
    gemm_out<<<gg, 256, 0, stream>>>(AOb, wob, bo, (float*)d_out);
}

// Round 26
// 157.349 us; speedup vs baseline: 1.0049x; 1.0049x over previous
//
#include <hip/hip_runtime.h>
#include <hip/hip_bf16.h>
#include <cstdint>

#define DM   1024
#define NH   16
#define DKK  64
#define BB   4
#define SS   2048

typedef __attribute__((ext_vector_type(8)))  short short8;
typedef __attribute__((ext_vector_type(4)))  float f32x4;
typedef __attribute__((ext_vector_type(16))) float f32x16;

__device__ __forceinline__ unsigned short f2bf(float f) {
    union { float f; uint32_t u; } v; v.f = f;
    uint32_t u = v.u;
    uint32_t r = (u + 0x7FFFu + ((u >> 16) & 1u)) >> 16;   // RNE
    return (unsigned short)r;
}

#define GLL(src, dst) __builtin_amdgcn_global_load_lds(                      \
        (__attribute__((address_space(1))) void*)(src),                      \
        (__attribute__((address_space(3))) void*)(dst), 16, 0, 0)

// ---------------- fp32 -> bf16 convert + PRE-SWIZZLE (4 weight matrices) ----------------
// W_sw[j][kb*8..] = W[j][kbs*8..], kbs = (kb&~7)|((kb^j)&7)
__global__ void cvt_w(const float* __restrict__ wq, const float* __restrict__ wk,
                      const float* __restrict__ wv, const float* __restrict__ wo,
                      unsigned short* __restrict__ dst)
{
    int i = blockIdx.x * 256 + threadIdx.x;      // 16B-block id: 4 * 1024 * 128
    int a = i >> 17;
    int r = i & 131071;
    int j = r >> 7, kb = r & 127;
    int kbs = (kb & ~7) | ((kb ^ j) & 7);
    const float* s = (a == 0 ? wq : a == 1 ? wk : a == 2 ? wv : wo) + (size_t)j * 1024 + kbs * 8;
    float4 f0 = *(const float4*)(s);
    float4 f1 = *(const float4*)(s + 4);
    union { uint32_t u[4]; short8 s8; } c;
    asm("v_cvt_pk_bf16_f32 %0, %1, %2" : "=v"(c.u[0]) : "v"(f0.x), "v"(f0.y));
    asm("v_cvt_pk_bf16_f32 %0, %1, %2" : "=v"(c.u[1]) : "v"(f0.z), "v"(f0.w));
    asm("v_cvt_pk_bf16_f32 %0, %1, %2" : "=v"(c.u[2]) : "v"(f1.x), "v"(f1.y));
    asm("v_cvt_pk_bf16_f32 %0, %1, %2" : "=v"(c.u[3]) : "v"(f1.z), "v"(f1.w));
    *(short8*)(dst + ((size_t)a << 20) + (size_t)j * 1024 + kb * 8) = c.s8;
}

// ------ merged QKV GEMM: 512 thr, DOUBLE-BUFFERED B, depth-2 reg-prefetched fp32 A ------
// r25 base + gemm_out-style B dbuf: B(t+1)->lB[(t+1)&1] issued at iter t, MFMA reads
// lB[t&1]. Ledger (fences pin order; in-order queue): at iter-t drain, queue =
// [B(t)2, A(t+1)4, B(t+1)2, A(t+2)4] = 12 -> vmcnt(10) retires exactly B(t).
// Buffer liveness: lB[(t+1)&1] last read at iter t-1's MFMA, two barriers earlier.
// Tail iters 14/15: vmcnt(0). LDS 48KB -> 3 blocks/CU (24 waves).
__global__ __launch_bounds__(512) void gemm_qkv(
        const float* __restrict__ Aq, const float* __restrict__ Ak, const float* __restrict__ Av,
        const unsigned short* __restrict__ Wq, const unsigned short* __restrict__ Wk,
        const unsigned short* __restrict__ Wv,
        const float* __restrict__ bq, const float* __restrict__ bk, const float* __restrict__ bv,
        unsigned short* __restrict__ Qo, unsigned short* __restrict__ Ko,
        unsigned short* __restrict__ Vo, const float qscale)
{
    const int orig = blockIdx.z * 512 + blockIdx.y * 8 + blockIdx.x;
    const int wid  = (orig & 7) * 192 + (orig >> 3);   // bijective XCD swizzle
    const int z    = wid >> 9;
    const int rem  = wid & 511;
    const int brow = (rem >> 3) * 128;
    const int bcol = (rem & 7) * 128;

    const float* A           = (z == 0) ? Aq : (z == 1) ? Ak : Av;
    const unsigned short* Bw = (z == 0) ? Wq : (z == 1) ? Wk : Wv;
    const float* bias        = (z == 0) ? bq : (z == 1) ? bk : bv;

    __shared__ __align__(16) unsigned short lA[128 * 64];
    __shared__ __align__(16) unsigned short lB[2][128 * 64];
    const int tid = threadIdx.x;
    const int w = tid >> 6, l = tid & 63;          // 8 waves
    const int wr = (w >> 1) * 32, wc = (w & 1) * 64;   // 4M x 2N, per-wave 32x64
    const int lrow = l & 15;
    const int hi = l >> 4;
    const int sr = l >> 3;
    const int scb = l & 7;
    f32x4 acc[2][4] = {};

    const float* aga[2];
    const unsigned short* bga[2];
    int awb[2], lbo[2];
#pragma unroll
    for (int i = 0; i < 2; ++i) {
        const int chunk = w * 2 + i;
        const int r = chunk * 8 + sr;
        aga[i] = A  + (size_t)(brow + r) * 1024 + scb * 8;
        bga[i] = Bw + (size_t)(bcol + r) * 1024 + scb * 8;
        awb[i] = chunk * 1024 + sr * 128 + ((scb ^ sr) << 4);
        lbo[i] = chunk * 512;
    }

    f32x4 aX[2][2], aY[2][2];   // [chunk][half] fp32 prefetch regs

#define QKV_LD(R, KT)                                                    \
    { _Pragma("unroll") for (int i = 0; i < 2; ++i) {                    \
        R[i][0] = *(const f32x4*)(aga[i] + (KT) * 64);                   \
        R[i][1] = *(const f32x4*)(aga[i] + (KT) * 64 + 4); } }

#define QKV_CVTWR(R)                                                     \
    { _Pragma("unroll") for (int i = 0; i < 2; ++i) {                    \
        union { uint32_t u[4]; short8 s8; } c;                           \
        asm("v_cvt_pk_bf16_f32 %0, %1, %2" : "=v"(c.u[0]) : "v"(R[i][0][0]), "v"(R[i][0][1])); \
        asm("v_cvt_pk_bf16_f32 %0, %1, %2" : "=v"(c.u[1]) : "v"(R[i][0][2]), "v"(R[i][0][3])); \
        asm("v_cvt_pk_bf16_f32 %0, %1, %2" : "=v"(c.u[2]) : "v"(R[i][1][0]), "v"(R[i][1][1])); \
        asm("v_cvt_pk_bf16_f32 %0, %1, %2" : "=v"(c.u[3]) : "v"(R[i][1][2]), "v"(R[i][1][3])); \
        *(short8*)((char*)lA + awb[i]) = c.s8; } }

#define QKV_MFMA(LB)                                                                          \
    {                                                                                         \
        const unsigned short* lb_ = (LB);                                                     \
        __builtin_amdgcn_s_setprio(1);                                                        \
        _Pragma("unroll") for (int kk = 0; kk < 2; ++kk) {                                    \
            short8 af[2], bf[4];                                                              \
            _Pragma("unroll") for (int m = 0; m < 2; ++m) {                                   \
                const int row = wr + m * 16 + lrow;                                           \
                const int pb = (kk * 4 + hi) ^ (row & 7);                                     \
                af[m] = *(const short8*)((const char*)lA + row * 128 + (pb << 4));            \
            }                                                                                 \
            _Pragma("unroll") for (int n = 0; n < 4; ++n) {                                   \
                const int row = wc + n * 16 + lrow;                                           \
                const int pb = (kk * 4 + hi) ^ (row & 7);                                     \
                bf[n] = *(const short8*)((const char*)lb_ + row * 128 + (pb << 4));           \
            }                                                                                 \
            _Pragma("unroll") for (int m = 0; m < 2; ++m)                                     \
            _Pragma("unroll") for (int n = 0; n < 4; ++n)                                     \
                acc[m][n] = __builtin_amdgcn_mfma_f32_16x16x32_bf16(af[m], bf[n], acc[m][n], 0, 0, 0); \
        }                                                                                     \
        __builtin_amdgcn_s_setprio(0);                                                        \
    }

    // prologue: B(0) -> lB[0]; X <- A(0); Y <- A(1)  (order pinned)
#pragma unroll
    for (int i = 0; i < 2; ++i) GLL(bga[i], lB[0] + lbo[i]);
    asm volatile("" ::: "memory");
    QKV_LD(aX, 0);
    QKV_LD(aY, 1);
    asm volatile("" ::: "memory");

    for (int t = 0; t < 14; t += 2) {
        // even iter t: issue B(t+1)->lB[(t+1)&1]; cvt X=A(t); reload X <- A(t+2)
#pragma unroll
        for (int i = 0; i < 2; ++i) GLL(bga[i] + (t + 1) * 64, lB[(t + 1) & 1] + lbo[i]);
        asm volatile("" ::: "memory");  // pin: B(t+1) before A(t+2)
        QKV_CVTWR(aX);
        QKV_LD(aX, t + 2);
        asm volatile("s_waitcnt vmcnt(10) lgkmcnt(0)" ::: "memory");   // retires B(t)
        __builtin_amdgcn_s_barrier();
        QKV_MFMA(lB[t & 1]);
        asm volatile("" ::: "memory");
        __builtin_amdgcn_s_barrier();
        // odd iter t+1: issue B(t+2)->lB[(t+2)&1]; cvt Y=A(t+1); reload Y <- A(t+3)
#pragma unroll
        for (int i = 0; i < 2; ++i) GLL(bga[i] + (t + 2) * 64, lB[(t + 2) & 1] + lbo[i]);
        asm volatile("" ::: "memory");
        QKV_CVTWR(aY);
        QKV_LD(aY, t + 3);
        asm volatile("s_waitcnt vmcnt(10) lgkmcnt(0)" ::: "memory");   // retires B(t+1)
        __builtin_amdgcn_s_barrier();
        QKV_MFMA(lB[(t + 1) & 1]);
        asm volatile("" ::: "memory");
        __builtin_amdgcn_s_barrier();
    }
    // tail iter 14: issue B(15)->lB[1]; cvt X=A(14); full drain (retires B(14)+B(15))
#pragma unroll
    for (int i = 0; i < 2; ++i) GLL(bga[i] + 15 * 64, lB[1] + lbo[i]);
    asm volatile("" ::: "memory");
    QKV_CVTWR(aX);
    asm volatile("s_waitcnt vmcnt(0) lgkmcnt(0)" ::: "memory");
    __builtin_amdgcn_s_barrier();
    QKV_MFMA(lB[0]);
    asm volatile("" ::: "memory");
    __builtin_amdgcn_s_barrier();
    // tail iter 15: cvt Y=A(15); B(15) already resident
    QKV_CVTWR(aY);
    asm volatile("s_waitcnt vmcnt(0) lgkmcnt(0)" ::: "memory");
    __builtin_amdgcn_s_barrier();
    QKV_MFMA(lB[1]);

#undef QKV_LD
#undef QKV_CVTWR
#undef QKV_MFMA

    const float ascale = (z == 0) ? qscale : 1.0f;
#pragma unroll
    for (int m = 0; m < 2; ++m) {
#pragma unroll
        for (int n = 0; n < 4; ++n) {
            const int i0 = brow + wr + m * 16 + hi * 4;
            const int j  = bcol + wc + n * 16 + lrow;
            const float bj = bias[j];
            const int hh = j >> 6, d = j & 63;
            if (z < 2) {
                unsigned short* Cb = (z == 0) ? Qo : Ko;
#pragma unroll
                for (int t = 0; t < 4; ++t) {
                    const int i = i0 + t;
                    const int b = i >> 11, s = i & 2047;
                    Cb[(((size_t)(b * NH + hh) * SS) + s) * DKK + d] = f2bf((acc[m][n][t] + bj) * ascale);
                }
            } else {   // V^T
                const int b = i0 >> 11, s0 = i0 & 2047;
                ushort4 pk;
                pk.x = f2bf(acc[m][n][0] + bj);
                pk.y = f2bf(acc[m][n][1] + bj);
                pk.z = f2bf(acc[m][n][2] + bj);
                pk.w = f2bf(acc[m][n][3] + bj);
                *(ushort4*)(Vo + (((size_t)(b * NH + hh) * DKK) + d) * SS + s0) = pk;
            }
        }
    }
}

// ---------------- final projection GEMM: bf16 A reg-staged swizzled, depth-2, fp32 out ------
__global__ __launch_bounds__(256) void gemm_out(
        const unsigned short* __restrict__ A,
        const unsigned short* __restrict__ Bw,
        const float* __restrict__ bias,
        float* __restrict__ Cout)
{
    const int orig = blockIdx.y * 8 + blockIdx.x;
    const int wid  = (orig & 7) * 64 + (orig >> 3);
    const int brow = (wid >> 3) * 128;
    const int bcol = (wid & 7) * 128;

    __shared__ __align__(16) unsigned short lA[128 * 64];
    __shared__ __align__(16) unsigned short lB[2][128 * 64];

    const int tid = threadIdx.x;
    const int w = tid >> 6, l = tid & 63;
    const int wr = (w >> 1) * 64, wc = (w & 1) * 64;
    const int lrow = l & 15;
    const int hi = l >> 4;
    const int sr = l >> 3, scb = l & 7;

    const unsigned short* aga[4];
    const unsigned short* bga[4];
    int awb[4], lbo[4];
#pragma unroll
    for (int i = 0; i < 4; ++i) {
        const int chunk = w * 4 + i;
        const int r = chunk * 8 + sr;
        aga[i] = A  + (size_t)(brow + r) * 1024 + scb * 8;
        bga[i] = Bw + (size_t)(bcol + r) * 1024 + scb * 8;
        awb[i] = chunk * 1024 + sr * 128 + ((scb ^ sr) << 4);
        lbo[i] = chunk * 512;
    }

    short8 aX[4], aY[4];
    f32x4 acc[4][4] = {};

#pragma unroll
    for (int i = 0; i < 4; ++i) GLL(bga[i], lB[0] + lbo[i]);
#pragma unroll
    for (int i = 0; i < 4; ++i) aX[i] = *(const short8*)(aga[i]);
#pragma unroll
    for (int i = 0; i < 4; ++i) aY[i] = *(const short8*)(aga[i] + 64);

#define OUT_WR(CUR)                                                     \
    _Pragma("unroll")                                                   \
    for (int i = 0; i < 4; ++i)                                         \
        *(short8*)((char*)lA + awb[i]) = CUR[i];

#define OUT_MFMA(LB)                                                                              \
    {                                                                                             \
        const unsigned short* lb = (LB);                                                          \
        __builtin_amdgcn_s_setprio(1);                                                            \
        _Pragma("unroll")                                                                         \
        for (int kk = 0; kk < 2; ++kk) {                                                          \
            short8 af[4], bf[4];                                                                  \
            _Pragma("unroll")                                                                     \
            for (int m = 0; m < 4; ++m) {                                                         \
                const int row = wr + m * 16 + lrow;                                               \
                const int pb = (kk * 4 + hi) ^ (row & 7);                                         \
                af[m] = *(const short8*)((const char*)lA + row * 128 + (pb << 4));                \
            }                                                                                     \
            _Pragma("unroll")                                                                     \
            for (int n = 0; n < 4; ++n) {                                                         \
                const int row = wc + n * 16 + lrow;                                               \
                const int pb = (kk * 4 + hi) ^ (row & 7);                                         \
                bf[n] = *(const short8*)((const char*)lb + row * 128 + (pb << 4));                \
            }                                                                                     \
            _Pragma("unroll")                                                                     \
            for (int m = 0; m < 4; ++m)                                                           \
                _Pragma("unroll")                                                                 \
                for (int n = 0; n < 4; ++n)                                                       \
                    acc[m][n] = __builtin_amdgcn_mfma_f32_16x16x32_bf16(af[m], bf[n], acc[m][n], 0, 0, 0); \
        }                                                                                         \
        __builtin_amdgcn_s_setprio(0);                                                            \
    }

    for (int t = 0; t < 14; t += 2) {
        OUT_WR(aX);
        {
            const int ko = (t + 2) * 64;
#pragma unroll
            for (int i = 0; i < 4; ++i) aX[i] = *(const short8*)(aga[i] + ko);
            const int kb = (t + 1) * 64;
#pragma unroll
            for (int i = 0; i < 4; ++i) GLL(bga[i] + kb, lB[1] + lbo[i]);
        }
        asm volatile("s_waitcnt vmcnt(8) lgkmcnt(0)" ::: "memory");
        __builtin_amdgcn_s_barrier();
        OUT_MFMA(lB[0]);
        asm volatile("" ::: "memory");
        __builtin_amdgcn_s_barrier();

        OUT_WR(aY);
        {
            const int ko = (t + 3) * 64;
#pragma unroll
            for (int i = 0; i < 4; ++i) aY[i] = *(const short8*)(aga[i] + ko);
            const int kb = (t + 2) * 64;
#pragma unroll
            for (int i = 0; i < 4; ++i) GLL(bga[i] + kb, lB[0] + lbo[i]);
        }
        asm volatile("s_waitcnt vmcnt(8) lgkmcnt(0)" ::: "memory");
        __builtin_amdgcn_s_barrier();
        OUT_MFMA(lB[1]);
        asm volatile("" ::: "memory");
        __builtin_amdgcn_s_barrier();
    }
    OUT_WR(aX);
#pragma unroll
    for (int i = 0; i < 4; ++i) GLL(bga[i] + 15 * 64, lB[1] + lbo[i]);
    asm volatile("s_waitcnt vmcnt(4) lgkmcnt(0)" ::: "memory");
    __builtin_amdgcn_s_barrier();
    OUT_MFMA(lB[0]);
    asm volatile("" ::: "memory");
    __builtin_amdgcn_s_barrier();
    OUT_WR(aY);
    asm volatile("s_waitcnt vmcnt(0) lgkmcnt(0)" ::: "memory");
    __builtin_amdgcn_s_barrier();
    OUT_MFMA(lB[1]);

#pragma unroll
    for (int m = 0; m < 4; ++m) {
#pragma unroll
        for (int n = 0; n < 4; ++n) {
            const int i0 = brow + wr + m * 16 + (l >> 4) * 4;
            const int j  = bcol + wc + n * 16 + lrow;
            const float bj = bias[j];
#pragma unroll
            for (int t = 0; t < 4; ++t)
                Cout[(size_t)(i0 + t) * DM + j] = acc[m][n][t] + bj;
        }
    }
#undef OUT_WR
#undef OUT_MFMA
}

// ---------------- causal flash attention (round-7, unchanged) ----------------
__global__ __launch_bounds__(256) void attn_kernel(
        const unsigned short* __restrict__ Q,
        const unsigned short* __restrict__ K,
        const unsigned short* __restrict__ Vt,
        unsigned short* __restrict__ AO)
{
    const int flat = blockIdx.y * 16 + blockIdx.x;      // grid (16, 64)
    const int r8 = flat & 7, k8 = flat >> 3;
    const int bh = r8 * 8 + (k8 & 7);                   // 8 heads per XCD-residue (L2 share)
    const int qchunk = 15 - (k8 >> 3);                  // LPT: long blocks first
    const int tid = threadIdx.x;
    const int w = tid >> 6, l = tid & 63;
    const int ln = l & 31, h = l >> 5;
    const int qb = qchunk * 128;
    const int q0w = qb + w * 32;

    __shared__ __align__(16) char lK[2][4096];
    __shared__ __align__(16) char lV[2][4096];

    const unsigned short* Qp = Q  + ((size_t)bh * SS + q0w) * DKK;
    const unsigned short* Kp = K  + (size_t)bh * SS * DKK;
    const unsigned short* Vp = Vt + (size_t)bh * DKK * SS;

    const int srow = tid >> 3, scb = tid & 7;
    const int swb = srow * 128 + ((scb * 16) ^ ((srow & 7) << 4));
    const unsigned short* ksrc = Kp + srow * DKK + scb * 8;            // + t*2048
    const int vd = (scb < 4) ? srow : (srow + 32);
    const unsigned short* vsrc = Vp + (size_t)vd * SS + (scb & 3) * 8; // + t*32

    int ka[4], va[4];
#pragma unroll
    for (int ks = 0; ks < 4; ++ks)
        ka[ks] = ln * 128 + ((ks * 32 + h * 16) ^ ((ln & 7) << 4));
#pragma unroll
    for (int c = 0; c < 4; ++c)
        va[c] = ln * 128 + ((c * 32 + h * 16) ^ ((ln & 7) << 4));

    short8 qf[4];
#pragma unroll
    for (int ks = 0; ks < 4; ++ks)
        qf[ks] = *(const short8*)(Qp + (size_t)ln * DKK + ks * 16 + h * 8);

    f32x16 o0 = {}, o1 = {};
    float lsum = 0.f;

    const int Tc = qb / 32;
    const int NT = Tc + 4;

    auto compute = [&](int t, int buf) {
        const char* kb = lK[buf];
        const char* vb = lV[buf];
        short8 kf[4];
#pragma unroll
        for (int ks = 0; ks < 4; ++ks) kf[ks] = *(const short8*)(kb + ka[ks]);

        f32x16 s = {};
        __builtin_amdgcn_s_setprio(1);
#pragma unroll
        for (int ks = 0; ks < 4; ++ks)
            s = __builtin_amdgcn_mfma_f32_32x32x16_bf16(kf[ks], qf[ks], s, 0, 0, 0);
        __builtin_amdgcn_s_setprio(0);

        const bool diag = (t == Tc + w);
#pragma unroll
        for (int r = 0; r < 16; ++r) {
            float e;
            asm("v_exp_f32 %0, %1" : "=v"(e) : "v"(s[r]));   // 2^s (Q pre-scaled)
            if (diag) {
                const int crow = (r & 3) + 8 * (r >> 2) + 4 * h;
                e = (crow > ln) ? 0.f : e;
            }
            s[r] = e;
            lsum += e;
        }

        uint32_t pk[8];
#pragma unroll
        for (int i = 0; i < 8; ++i) {
            uint32_t d;
            asm("v_cvt_pk_bf16_f32 %0, %1, %2" : "=v"(d) : "v"(s[2 * i]), "v"(s[2 * i + 1]));
            pk[i] = d;
        }
        asm("v_permlane32_swap_b32 %0, %1" : "+v"(pk[0]), "+v"(pk[2]));
        asm("v_permlane32_swap_b32 %0, %1" : "+v"(pk[1]), "+v"(pk[3]));
        asm("v_permlane32_swap_b32 %0, %1" : "+v"(pk[4]), "+v"(pk[6]));
        asm("v_permlane32_swap_b32 %0, %1" : "+v"(pk[5]), "+v"(pk[7]));

        union Ux { uint32_t u[4]; short8 s8; } pa0, pa1;
        pa0.u[0] = pk[0]; pa0.u[1] = pk[1]; pa0.u[2] = pk[2]; pa0.u[3] = pk[3];
        pa1.u[0] = pk[4]; pa1.u[1] = pk[5]; pa1.u[2] = pk[6]; pa1.u[3] = pk[7];

        short8 vf00 = *(const short8*)(vb + va[0]);
        short8 vf10 = *(const short8*)(vb + va[1]);
        short8 vf01 = *(const short8*)(vb + va[2]);
        short8 vf11 = *(const short8*)(vb + va[3]);

        __builtin_amdgcn_s_setprio(1);
        o0 = __builtin_amdgcn_mfma_f32_32x32x16_bf16(pa0.s8, vf00, o0, 0, 0, 0);
        o0 = __builtin_amdgcn_mfma_f32_32x32x16_bf16(pa1.s8, vf10, o0, 0, 0, 0);
        o1 = __builtin_amdgcn_mfma_f32_32x32x16_bf16(pa0.s8, vf01, o1, 0, 0, 0);
        o1 = __builtin_amdgcn_mfma_f32_32x32x16_bf16(pa1.s8, vf11, o1, 0, 0, 0);
        __builtin_amdgcn_s_setprio(0);
    };

    short8 kA = *(const short8*)(ksrc);
    short8 vA = *(const short8*)(vsrc);
    *(short8*)(&lK[0][swb]) = kA;
    *(short8*)(&lV[0][swb]) = vA;
    kA = *(const short8*)(ksrc + 2048);
    vA = *(const short8*)(vsrc + 32);
    short8 kB = {}, vB = {};
    __syncthreads();

    int t = 0, buf = 0;
    for (;;) {
        if (t + 2 < NT) {
            kB = *(const short8*)(ksrc + (size_t)(t + 2) * 2048);
            vB = *(const short8*)(vsrc + (size_t)(t + 2) * 32);
        }
        if (t <= Tc + w) compute(t, buf);
        if (t + 1 < NT) {
            *(short8*)(&lK[buf ^ 1][swb]) = kA;
            *(short8*)(&lV[buf ^ 1][swb]) = vA;
        }
        __syncthreads();
        buf ^= 1;
        if (++t == NT) break;

        if (t + 2 < NT) {
            kA = *(const short8*)(ksrc + (size_t)(t + 2) * 2048);
            vA = *(const short8*)(vsrc + (size_t)(t + 2) * 32);
        }
        if (t <= Tc + w) compute(t, buf);
        if (t + 1 < NT) {
            *(short8*)(&lK[buf ^ 1][swb]) = kB;
            *(short8*)(&lV[buf ^ 1][swb]) = vB;
        }
        __syncthreads();
        buf ^= 1;
        if (++t == NT) break;
    }

    lsum += __shfl_xor(lsum, 32, 64);
    const float rcp = 1.0f / lsum;

    const int bb = bh >> 4, hh = bh & 15;
#pragma unroll
    for (int r = 0; r < 16; ++r) {
        const int crow = (r & 3) + 8 * (r >> 2) + 4 * h;
        const float rl = __shfl(rcp, crow, 64);
        const size_t row = (size_t)(bb * SS + q0w + crow) * DM + hh * DKK;
        AO[row + ln]      = f2bf(o0[r] * rl);
        AO[row + 32 + ln] = f2bf(o1[r] * rl);
    }
}

extern "C" void kernel_launch(void* const* d_in, const int* in_sizes, int n_in,
                              void* d_out, int out_size, void* d_ws, size_t ws_size,
                              hipStream_t stream)
{
    const float* query  = (const float*)d_in[0];
    const float* key_in = (const float*)d_in[1];
    const float* value  = (const float*)d_in[2];
    const float* Wq = (const float*)d_in[3];
    const float* bq = (const float*)d_in[4];
    const float* Wk = (const float*)d_in[5];
    const float* bk = (const float*)d_in[6];
    const float* Wv = (const float*)d_in[7];
    const float* bv = (const float*)d_in[8];
    const float* Wo = (const float*)d_in[9];
    const float* bo = (const float*)d_in[10];

    const size_t NACT = (size_t)BB * SS * DM;   // 8388608
    const size_t NWT  = (size_t)DM * DM;        // 1048576

    unsigned short* ws  = (unsigned short*)d_ws;
    unsigned short* wqb = ws;
    unsigned short* wkb = wqb + NWT;
    unsigned short* wvb = wkb + NWT;
    unsigned short* wob = wvb + NWT;
    unsigned short* Qb  = wob + NWT;
    unsigned short* Kb  = Qb + NACT;
    unsigned short* Vtb = Kb + NACT;
    unsigned short* AOb = Vtb + NACT;

    cvt_w<<<2048, 256, 0, stream>>>(Wq, Wk, Wv, Wo, ws);

    const float QSCALE = 0.125f * 1.44269504088896f;   // 1/sqrt(64) * log2(e)
    dim3 gq(8, 64, 3);   // 1536 blocks
    gemm_qkv<<<gq, 512, 0, stream>>>(query, key_in, value, wqb, wkb, wvb,
                                     bq, bk, bv, Qb, Kb, Vtb, QSCALE);

    attn_kernel<<<dim3(16, 64), 256, 0, stream>>>(Qb, Kb, Vtb, AOb);

    dim3 gg(DM / 128, (BB * SS) / 128);   // (8, 64)
    gemm_out<<<gg, 256, 0, stream>>>(AOb, wob, bo, (float*)d_out);
}